// Round 1
// baseline (146.586 us; speedup 1.0000x reference)
//
#include <hip/hip_runtime.h>
#include <hip/hip_cooperative_groups.h>

namespace cg = cooperative_groups;

// SeparationLoss: mean over B of sum_{i!=j} max(0, thr^2 - ||kp_i - kp_j||^2)
// B = 131072, J = 17, 3 floats per joint -> 51 floats per batch.
//
// Single cooperative kernel (was two-pass):
//   phase 1: 512 blocks x 256 threads, 256 batches/block staged via LDS;
//            block partial -> agent-scope release store to d_ws[blockIdx].
//   grid.sync()
//   phase 2: block 0 reduces 512 partials (acquire loads), stores mean.
// No atomics on a shared accumulator, no d_out memset, one dispatch total.

#define NJ      17
#define KPF     51          // floats per batch (17*3)
#define BPB     256         // batches per block
#define THREADS 256
#define NPART   512         // grid = B / BPB; 52.3KB LDS -> 3 blk/CU cap = 768 >= 512

__global__ __launch_bounds__(THREADS)
void sep_loss_fused(const float* __restrict__ kps,
                    float* __restrict__ partial,
                    float* __restrict__ out,
                    float thr2, float scale /* 2/B */) {
    __shared__ float lds[BPB * KPF];            // 52224 B
    __shared__ float wsum[THREADS / 64];

    const int tid = threadIdx.x;
    const long long b0 = (long long)blockIdx.x * BPB;

    // ---- Stage 256 batches (contiguous, 16B-aligned) ----
    const float4* __restrict__ src4 =
        reinterpret_cast<const float4*>(kps + b0 * KPF);
    float4* dst4 = reinterpret_cast<float4*>(lds);
    const int n4 = BPB * KPF / 4;               // 3264 float4s
    for (int i = tid; i < n4; i += THREADS) dst4[i] = src4[i];
    __syncthreads();

    // ---- One batch per thread; row stride 51 (odd) -> benign LDS banking ----
    float kp[KPF];
    const float* my = lds + tid * KPF;
    #pragma unroll
    for (int k = 0; k < KPF; ++k) kp[k] = my[k];

    // m_i = thr2/2 - ||kp_i||^2 ; pair value = max(0, m_i + m_j + 2*dot)
    float m[NJ];
    #pragma unroll
    for (int i = 0; i < NJ; ++i) {
        float x = kp[i * 3], y = kp[i * 3 + 1], z = kp[i * 3 + 2];
        m[i] = 0.5f * thr2 - fmaf(x, x, fmaf(y, y, z * z));
    }

    float acc = 0.0f;
    #pragma unroll
    for (int i = 0; i < NJ; ++i) {
        #pragma unroll
        for (int j = i + 1; j < NJ; ++j) {
            float dot = fmaf(kp[i * 3],     kp[j * 3],
                       fmaf(kp[i * 3 + 1], kp[j * 3 + 1],
                            kp[i * 3 + 2] * kp[j * 3 + 2]));
            acc += fmaxf(fmaf(2.0f, dot, m[i] + m[j]), 0.0f);
        }
    }

    // ---- Block reduction -> one agent-scope release store ----
    #pragma unroll
    for (int off = 32; off > 0; off >>= 1)
        acc += __shfl_down(acc, off, 64);
    if ((tid & 63) == 0) wsum[tid >> 6] = acc;
    __syncthreads();
    if (tid == 0) {
        float s = wsum[0] + wsum[1] + wsum[2] + wsum[3];
        // per-XCD L2s are not coherent: publish with device(agent)-scope release
        __hip_atomic_store(&partial[blockIdx.x], s,
                           __ATOMIC_RELEASE, __HIP_MEMORY_SCOPE_AGENT);
    }

    // ---- Grid-wide barrier, then block 0 finishes ----
    cg::this_grid().sync();

    if (blockIdx.x == 0) {
        float a = __hip_atomic_load(&partial[tid],
                                    __ATOMIC_ACQUIRE, __HIP_MEMORY_SCOPE_AGENT)
                + __hip_atomic_load(&partial[tid + THREADS],
                                    __ATOMIC_ACQUIRE, __HIP_MEMORY_SCOPE_AGENT);
        #pragma unroll
        for (int off = 32; off > 0; off >>= 1)
            a += __shfl_down(a, off, 64);
        if ((tid & 63) == 0) wsum[tid >> 6] = a;
        __syncthreads();
        if (tid == 0)
            out[0] = (wsum[0] + wsum[1] + wsum[2] + wsum[3]) * scale;
    }
}

extern "C" void kernel_launch(void* const* d_in, const int* in_sizes, int n_in,
                              void* d_out, int out_size, void* d_ws, size_t ws_size,
                              hipStream_t stream) {
    const float* kps = (const float*)d_in[0];
    float* out = (float*)d_out;
    float* partial = (float*)d_ws;              // 512 floats of scratch

    const int B = in_sizes[0] / KPF;            // 131072
    float thr2 = 0.1f * 0.1f;                   // THRESHOLD^2
    float scale = 2.0f / (float)B;

    void* args[] = { (void*)&kps, (void*)&partial, (void*)&out,
                     (void*)&thr2, (void*)&scale };
    hipLaunchCooperativeKernel(reinterpret_cast<void*>(sep_loss_fused),
                               dim3(NPART), dim3(THREADS),
                               args, 0, stream);
}

// Round 3
// 85.336 us; speedup vs baseline: 1.7177x; 1.7177x over previous
//
#include <hip/hip_runtime.h>

// SeparationLoss: mean over B of sum_{i!=j} max(0, thr^2 - ||kp_i - kp_j||^2)
// B = 131072, J = 17, 3 floats per joint -> 51 floats per batch.
//
// Single compute dispatch + 4-byte memset node (graph-capture-safe):
//   - hipMemsetAsync zeroes ws[0] (block-completion counter) each rep.
//   - 512 blocks x 256 threads; each wave stages its own 64 batches to LDS
//     (wave-local s_waitcnt lgkmcnt(0), no block barrier), 1 batch/thread.
//   - block partial -> agent-scope release store to ws[16+blockIdx].
//   - tid0: prev = fetch_add(counter, ACQ_REL, agent). prev==511 => this is
//     the last-finishing block; its RMW synchronizes with all 511 earlier
//     RMWs (release sequence), so every partial is visible. It reduces the
//     512 partials and writes the mean. No spin => deadlock-free regardless
//     of co-residency or dispatch order (per-XCD L2 non-coherence handled
//     by agent-scope atomics).
//
// NOTE (R1 lesson): cooperative grid.sync() costs ~70us on this chip -- never
// worth it here. R2's poison-probe counter-init was removed: it assumed the
// harness poison is a uniform dword, which is unverifiable; memset-init is
// assumption-free.

#define NJ      17
#define KPF     51          // floats per batch (17*3)
#define BPB     256         // batches per block
#define THREADS 256
#define NPART   512         // grid = B / BPB
#define POFF    16          // partials start at ws[16] (counter isolated in own line)

__global__ __launch_bounds__(THREADS)
void sep_loss_onepass(const float* __restrict__ kps,
                      float* __restrict__ ws,
                      float* __restrict__ out,
                      float thr2, float scale /* 2/B */) {
    __shared__ float lds[BPB * KPF];            // 52224 B
    __shared__ float wsum[THREADS / 64];
    __shared__ int is_last;

    const int tid  = threadIdx.x;
    const int lane = tid & 63;
    const int w    = tid >> 6;
    const long long b0 = (long long)blockIdx.x * BPB;

    // ---- Per-wave staging: wave w stages its own 64 batches (13056 B) ----
    {
        const float4* __restrict__ src4 = reinterpret_cast<const float4*>(
            kps + (b0 + (long long)w * 64) * KPF);
        float4* dst4 = reinterpret_cast<float4*>(lds + w * 64 * KPF);
        #pragma unroll
        for (int i = lane; i < 64 * KPF / 4; i += 64)   // 816 float4s / wave
            dst4[i] = src4[i];
    }
    // Wave only reads rows it wrote: wave-local LDS drain, no __syncthreads.
    __asm__ volatile("s_waitcnt lgkmcnt(0)" ::: "memory");
    __builtin_amdgcn_sched_barrier(0);

    // ---- One batch per thread; row stride 51 (odd) -> benign LDS banking ----
    float kp[KPF];
    const float* my = lds + (w * 64 + lane) * KPF;
    #pragma unroll
    for (int k = 0; k < KPF; ++k) kp[k] = my[k];

    // m_i = thr2/2 - ||kp_i||^2 ; pair value = max(0, m_i + m_j + 2*dot)
    float m[NJ];
    #pragma unroll
    for (int i = 0; i < NJ; ++i) {
        float x = kp[i * 3], y = kp[i * 3 + 1], z = kp[i * 3 + 2];
        m[i] = 0.5f * thr2 - fmaf(x, x, fmaf(y, y, z * z));
    }

    float acc = 0.0f;
    #pragma unroll
    for (int i = 0; i < NJ; ++i) {
        #pragma unroll
        for (int j = i + 1; j < NJ; ++j) {
            float dot = fmaf(kp[i * 3],     kp[j * 3],
                       fmaf(kp[i * 3 + 1], kp[j * 3 + 1],
                            kp[i * 3 + 2] * kp[j * 3 + 2]));
            acc += fmaxf(fmaf(2.0f, dot, m[i] + m[j]), 0.0f);
        }
    }

    // ---- Block reduction ----
    #pragma unroll
    for (int off = 32; off > 0; off >>= 1)
        acc += __shfl_down(acc, off, 64);
    if (lane == 0) wsum[w] = acc;
    __syncthreads();

    unsigned* counter = reinterpret_cast<unsigned*>(ws);     // memset to 0
    float*    partial = ws + POFF;                           // 512 floats

    if (tid == 0) {
        float s = wsum[0] + wsum[1] + wsum[2] + wsum[3];
        // per-XCD L2s not coherent: publish with agent-scope release
        __hip_atomic_store(&partial[blockIdx.x], s,
                           __ATOMIC_RELEASE, __HIP_MEMORY_SCOPE_AGENT);
        unsigned prev = __hip_atomic_fetch_add(counter, 1u,
                           __ATOMIC_ACQ_REL, __HIP_MEMORY_SCOPE_AGENT);
        is_last = (prev == NPART - 1) ? 1 : 0;
    }
    __syncthreads();

    // ---- Last-finishing block does the 512 -> 1 reduce inline ----
    if (is_last) {
        float a = __hip_atomic_load(&partial[tid],
                      __ATOMIC_ACQUIRE, __HIP_MEMORY_SCOPE_AGENT)
                + __hip_atomic_load(&partial[tid + THREADS],
                      __ATOMIC_ACQUIRE, __HIP_MEMORY_SCOPE_AGENT);
        #pragma unroll
        for (int off = 32; off > 0; off >>= 1)
            a += __shfl_down(a, off, 64);
        if (lane == 0) wsum[w] = a;
        __syncthreads();
        if (tid == 0)
            out[0] = (wsum[0] + wsum[1] + wsum[2] + wsum[3]) * scale;
    }
}

extern "C" void kernel_launch(void* const* d_in, const int* in_sizes, int n_in,
                              void* d_out, int out_size, void* d_ws, size_t ws_size,
                              hipStream_t stream) {
    const float* kps = (const float*)d_in[0];
    float* out = (float*)d_out;
    float* ws  = (float*)d_ws;   // [0] counter, [16..527] partials

    const int B = in_sizes[0] / KPF;            // 131072
    const float thr2  = 0.1f * 0.1f;            // THRESHOLD^2
    const float scale = 2.0f / (float)B;

    // Known counter init each rep (tiny memset node; capture-safe).
    hipMemsetAsync(d_ws, 0, 4, stream);
    sep_loss_onepass<<<NPART, THREADS, 0, stream>>>(kps, ws, out, thr2, scale);
}

// Round 4
// 74.117 us; speedup vs baseline: 1.9778x; 1.1514x over previous
//
#include <hip/hip_runtime.h>

// SeparationLoss: mean over B of sum_{i!=j} max(0, thr^2 - ||kp_i - kp_j||^2)
// B = 131072, J = 17, 3 floats per joint -> 51 floats per batch.
//
// Two-pass, atomic-free (verified structure from R0 @ 72.4us):
//   pass 1: 512 blocks x 256 threads; each WAVE stages its own 64 batches to
//           LDS (wave-local s_waitcnt lgkmcnt(0), no block-wide barrier so no
//           cross-wave straggler wait), 1 batch/thread compute;
//           block partial -> plain store to d_ws[blockIdx] (overwrites poison).
//   pass 2: 1 block x 64 threads (single wave, zero barriers) reduces 512
//           partials, stores mean.
//
// Session ledger (do NOT revisit):
//   R1: cooperative grid.sync = ~70us on this chip -> never worth it.
//   R3: 512 same-address agent-scope fetch_adds (last-block-done) = +13us
//       cross-XCD RMW serialization tail; memset node also not free.
//   => two-pass with plain stores is the right structure; only its internals
//      are worth tuning.

#define NJ      17
#define KPF     51          // floats per batch (17*3)
#define BPB     256         // batches per block (pass 1)
#define THREADS 256
#define NPART   512         // pass-1 grid = B / BPB

__global__ __launch_bounds__(THREADS)
void sep_loss_partial(const float* __restrict__ kps,
                      float* __restrict__ partial,
                      float thr2) {
    __shared__ float lds[BPB * KPF];            // 52224 B
    __shared__ float wsum[THREADS / 64];

    const int tid  = threadIdx.x;
    const int lane = tid & 63;
    const int w    = tid >> 6;
    const long long b0 = (long long)blockIdx.x * BPB;

    // ---- Per-wave staging: wave w stages its own 64 batches (13056 B) ----
    {
        const float4* __restrict__ src4 = reinterpret_cast<const float4*>(
            kps + (b0 + (long long)w * 64) * KPF);
        float4* dst4 = reinterpret_cast<float4*>(lds + w * 64 * KPF);
        #pragma unroll
        for (int i = lane; i < 64 * KPF / 4; i += 64)   // 816 float4s / wave
            dst4[i] = src4[i];
    }
    // Wave only reads rows it wrote: wave-local LDS drain, no __syncthreads.
    __asm__ volatile("s_waitcnt lgkmcnt(0)" ::: "memory");
    __builtin_amdgcn_sched_barrier(0);

    // ---- One batch per thread; row stride 51 (odd) -> benign LDS banking ----
    float kp[KPF];
    const float* my = lds + (w * 64 + lane) * KPF;
    #pragma unroll
    for (int k = 0; k < KPF; ++k) kp[k] = my[k];

    // m_i = thr2/2 - ||kp_i||^2 ; pair value = max(0, m_i + m_j + 2*dot)
    float m[NJ];
    #pragma unroll
    for (int i = 0; i < NJ; ++i) {
        float x = kp[i * 3], y = kp[i * 3 + 1], z = kp[i * 3 + 2];
        m[i] = 0.5f * thr2 - fmaf(x, x, fmaf(y, y, z * z));
    }

    float acc = 0.0f;
    #pragma unroll
    for (int i = 0; i < NJ; ++i) {
        #pragma unroll
        for (int j = i + 1; j < NJ; ++j) {
            float dot = fmaf(kp[i * 3],     kp[j * 3],
                       fmaf(kp[i * 3 + 1], kp[j * 3 + 1],
                            kp[i * 3 + 2] * kp[j * 3 + 2]));
            acc += fmaxf(fmaf(2.0f, dot, m[i] + m[j]), 0.0f);
        }
    }

    // ---- Block reduction -> one plain store ----
    #pragma unroll
    for (int off = 32; off > 0; off >>= 1)
        acc += __shfl_down(acc, off, 64);
    if (lane == 0) wsum[w] = acc;
    __syncthreads();
    if (tid == 0)
        partial[blockIdx.x] = wsum[0] + wsum[1] + wsum[2] + wsum[3];
}

__global__ __launch_bounds__(64)
void sep_loss_final(const float* __restrict__ partial,
                    float* __restrict__ out,
                    float scale /* 2/B */) {
    const int lane = threadIdx.x;               // single wave, no barriers
    float acc = 0.0f;
    #pragma unroll
    for (int k = 0; k < NPART / 64; ++k)        // 8 partials per lane
        acc += partial[lane + 64 * k];
    #pragma unroll
    for (int off = 32; off > 0; off >>= 1)
        acc += __shfl_down(acc, off, 64);
    if (lane == 0)
        out[0] = acc * scale;
}

extern "C" void kernel_launch(void* const* d_in, const int* in_sizes, int n_in,
                              void* d_out, int out_size, void* d_ws, size_t ws_size,
                              hipStream_t stream) {
    const float* kps = (const float*)d_in[0];
    float* out = (float*)d_out;
    float* partial = (float*)d_ws;              // 512 floats of scratch

    const int B = in_sizes[0] / KPF;            // 131072
    const float thr2  = 0.1f * 0.1f;            // THRESHOLD^2
    const float scale = 2.0f / (float)B;

    sep_loss_partial<<<NPART, THREADS, 0, stream>>>(kps, partial, thr2);
    sep_loss_final<<<1, 64, 0, stream>>>(partial, out, scale);
}

// Round 5
// 72.774 us; speedup vs baseline: 2.0142x; 1.0184x over previous
//
#include <hip/hip_runtime.h>

// SeparationLoss: mean over B of sum_{i!=j} max(0, thr^2 - ||kp_i - kp_j||^2)
// B = 131072, J = 17, 3 floats per joint -> 51 floats per batch.
//
// Two-pass, atomic-free (best-verified structure: 72.4us @ R0):
//   pass 1: 512 blocks x 256 threads, 256 batches/block staged via LDS;
//           block partial -> plain store to d_ws[blockIdx] (overwrites poison).
//   pass 2: 1 block x 256 threads reduces 512 partials, stores mean to d_out.
// No atomicAdd (same-address RMW serializes at L2 across XCDs), no d_out memset.
//
// Session ledger (measured on MI355X -- do NOT revisit):
//   R1: cooperative grid.sync() = ~70us/kernel on this chip. Never worth it.
//   R3: last-block-done via 512 same-address agent-scope fetch_adds = +13us
//       (cross-XCD RMW serialization tail) + memset node cost.
//   R4: per-wave staging (no block barrier) + 1-wave pass 2 = neutral/noise
//       (-0: staging is HBM-bound, not barrier-bound).
//   Roofline: timed window is dominated by harness poison fills (268 MB at
//   75-78% HBM peak, ~44us) + input restore; our two kernels sum to ~10us
//   vs a ~7us arithmetic floor (26.7 MB input read + two launches).

#define NJ      17
#define KPF     51          // floats per batch (17*3)
#define BPB     256         // batches per block (pass 1)
#define THREADS 256
#define NPART   512         // pass-1 grid = B / BPB

__global__ __launch_bounds__(THREADS)
void sep_loss_partial(const float* __restrict__ kps,
                      float* __restrict__ partial,
                      float thr2) {
    __shared__ float lds[BPB * KPF];            // 52224 B
    __shared__ float wsum[THREADS / 64];

    const int tid = threadIdx.x;
    const long long b0 = (long long)blockIdx.x * BPB;

    // ---- Stage 256 batches (contiguous, 16B-aligned) ----
    const float4* __restrict__ src4 =
        reinterpret_cast<const float4*>(kps + b0 * KPF);
    float4* dst4 = reinterpret_cast<float4*>(lds);
    const int n4 = BPB * KPF / 4;               // 3264 float4s
    for (int i = tid; i < n4; i += THREADS) dst4[i] = src4[i];
    __syncthreads();

    // ---- One batch per thread; row stride 51 (odd) -> benign LDS banking ----
    float kp[KPF];
    const float* my = lds + tid * KPF;
    #pragma unroll
    for (int k = 0; k < KPF; ++k) kp[k] = my[k];

    // m_i = thr2/2 - ||kp_i||^2 ; pair value = max(0, m_i + m_j + 2*dot)
    float m[NJ];
    #pragma unroll
    for (int i = 0; i < NJ; ++i) {
        float x = kp[i * 3], y = kp[i * 3 + 1], z = kp[i * 3 + 2];
        m[i] = 0.5f * thr2 - fmaf(x, x, fmaf(y, y, z * z));
    }

    float acc = 0.0f;
    #pragma unroll
    for (int i = 0; i < NJ; ++i) {
        #pragma unroll
        for (int j = i + 1; j < NJ; ++j) {
            float dot = fmaf(kp[i * 3],     kp[j * 3],
                       fmaf(kp[i * 3 + 1], kp[j * 3 + 1],
                            kp[i * 3 + 2] * kp[j * 3 + 2]));
            acc += fmaxf(fmaf(2.0f, dot, m[i] + m[j]), 0.0f);
        }
    }

    // ---- Block reduction -> one plain store ----
    #pragma unroll
    for (int off = 32; off > 0; off >>= 1)
        acc += __shfl_down(acc, off, 64);
    if ((tid & 63) == 0) wsum[tid >> 6] = acc;
    __syncthreads();
    if (tid == 0) {
        float s = wsum[0] + wsum[1] + wsum[2] + wsum[3];
        partial[blockIdx.x] = s;
    }
}

__global__ __launch_bounds__(THREADS)
void sep_loss_final(const float* __restrict__ partial,
                    float* __restrict__ out,
                    float scale /* 2/B */) {
    __shared__ float wsum[THREADS / 64];
    const int tid = threadIdx.x;

    float acc = partial[tid] + partial[tid + THREADS];   // 512 partials
    #pragma unroll
    for (int off = 32; off > 0; off >>= 1)
        acc += __shfl_down(acc, off, 64);
    if ((tid & 63) == 0) wsum[tid >> 6] = acc;
    __syncthreads();
    if (tid == 0)
        out[0] = (wsum[0] + wsum[1] + wsum[2] + wsum[3]) * scale;
}

extern "C" void kernel_launch(void* const* d_in, const int* in_sizes, int n_in,
                              void* d_out, int out_size, void* d_ws, size_t ws_size,
                              hipStream_t stream) {
    const float* kps = (const float*)d_in[0];
    float* out = (float*)d_out;
    float* partial = (float*)d_ws;              // 512 floats of scratch

    const int B = in_sizes[0] / KPF;            // 131072
    const float thr2 = 0.1f * 0.1f;             // THRESHOLD^2
    const float scale = 2.0f / (float)B;

    const int grid = B / BPB;                   // 512
    sep_loss_partial<<<grid, THREADS, 0, stream>>>(kps, partial, thr2);
    sep_loss_final<<<1, THREADS, 0, stream>>>(partial, out, scale);
}